// Round 1
// baseline (1157.052 us; speedup 1.0000x reference)
//
#include <hip/hip_runtime.h>
#include <hip/hip_bf16.h>

// Problem constants
#define BB  2
#define LL  1024
#define DMM 768
#define DII 1536
#define NSS 16
#define DTRR 48
#define XZN (2*DII)        // 3072
#define XDN (DTRR+2*NSS)   // 80
#define NROWS (BB*LL)      // 2048

__device__ __forceinline__ float dspf(float x) {
    return 0.25f * (x + sqrtf(x*x + 4.0f));
}
__device__ __forceinline__ float clampf(float x, float lo, float hi) {
    return fminf(fmaxf(x, lo), hi);
}

// ---------------------------------------------------------------------------
// K1: norm.  one block per row (B*L rows of DM)
// ---------------------------------------------------------------------------
__global__ __launch_bounds__(256) void k_norm(const float* __restrict__ hs,
                                              const float* __restrict__ gamma,
                                              float* __restrict__ out) {
    int row = blockIdx.x;
    const float* p = hs + (size_t)row * DMM;
    __shared__ float red[256];
    int tid = threadIdx.x;

    float s = 0.f;
    for (int i = tid; i < DMM; i += 256) s += p[i];
    red[tid] = s; __syncthreads();
    for (int off = 128; off > 0; off >>= 1) {
        if (tid < off) red[tid] += red[tid + off];
        __syncthreads();
    }
    float mean = red[0] / (float)DMM;
    __syncthreads();

    float v = 0.f;
    for (int i = tid; i < DMM; i += 256) { float d = p[i] - mean; v += d*d; }
    red[tid] = v; __syncthreads();
    for (int off = 128; off > 0; off >>= 1) {
        if (tid < off) red[tid] += red[tid + off];
        __syncthreads();
    }
    float var = red[0] / (float)DMM;
    float k = rintf(log2f(sqrtf(var + 1e-9f)));   // round-half-even like jnp.round
    k = fmaxf(k, 0.f);
    float scale = exp2f(-k);
    for (int i = tid; i < DMM; i += 256)
        out[(size_t)row * DMM + i] = (p[i] - mean) * scale * gamma[i];
}

// ---------------------------------------------------------------------------
// Generic tiled fp32 GEMM:  C[M,N] = A[M,K] * B[N,K]^T + bias[N]
// 64x64 tile, KS=16, 256 threads, 4x4 per thread. K-major LDS => float4 reads.
// ---------------------------------------------------------------------------
__global__ __launch_bounds__(256) void k_gemm_tn(
    const float* __restrict__ A, int lda,
    const float* __restrict__ Bw, int ldb,
    const float* __restrict__ bias,
    float* __restrict__ C, int ldc,
    int M, int N, int K)
{
    const int TS = 64, KS = 16;
    __shared__ float As[KS][TS + 4];
    __shared__ float Bs[KS][TS + 4];
    int bm = blockIdx.y * TS, bn = blockIdx.x * TS;
    int tid = threadIdx.x;
    int tx = tid & 15, ty = tid >> 4;
    float acc[4][4] = {{0.f}};

    for (int k0 = 0; k0 < K; k0 += KS) {
        for (int i = tid; i < TS * KS; i += 256) {
            int c = i & (KS - 1), r = i >> 4;
            int gr = bm + r, gc = k0 + c;
            As[c][r] = (gr < M && gc < K) ? A[(size_t)gr * lda + gc] : 0.f;
        }
        for (int i = tid; i < TS * KS; i += 256) {
            int c = i & (KS - 1), r = i >> 4;
            int gr = bn + r, gc = k0 + c;
            Bs[c][r] = (gr < N && gc < K) ? Bw[(size_t)gr * ldb + gc] : 0.f;
        }
        __syncthreads();
        #pragma unroll
        for (int k = 0; k < KS; ++k) {
            const float4 av = *reinterpret_cast<const float4*>(&As[k][ty * 4]);
            const float4 bv = *reinterpret_cast<const float4*>(&Bs[k][tx * 4]);
            const float a0[4] = {av.x, av.y, av.z, av.w};
            const float b0[4] = {bv.x, bv.y, bv.z, bv.w};
            #pragma unroll
            for (int i = 0; i < 4; ++i)
                #pragma unroll
                for (int j = 0; j < 4; ++j)
                    acc[i][j] = fmaf(a0[i], b0[j], acc[i][j]);
        }
        __syncthreads();
    }
    #pragma unroll
    for (int i = 0; i < 4; ++i)
        #pragma unroll
        for (int j = 0; j < 4; ++j) {
            int gr = bm + ty * 4 + i, gc = bn + tx * 4 + j;
            if (gr < M && gc < N)
                C[(size_t)gr * ldc + gc] = acc[i][j] + bias[gc];
        }
}

// ---------------------------------------------------------------------------
// K3: depthwise causal conv (k=4, left pad 3) + dsp activation
// x comes from xz[:, 0:DI]
// ---------------------------------------------------------------------------
__global__ __launch_bounds__(256) void k_conv(const float* __restrict__ xz,
                                              const float* __restrict__ cw,
                                              const float* __restrict__ cb,
                                              float* __restrict__ xact)
{
    int idx = blockIdx.x * 256 + threadIdx.x;       // over B*L*DI
    if (idx >= NROWS * DII) return;
    int c = idx % DII;
    int bl = idx / DII;
    int l = bl % LL;
    int b = bl / LL;
    float acc = cb[c];
    #pragma unroll
    for (int j = 0; j < 4; ++j) {
        int ls = l - 3 + j;
        if (ls >= 0)
            acc = fmaf(xz[(size_t)(b * LL + ls) * XZN + c], cw[c * 4 + j], acc);
    }
    xact[idx] = dspf(acc);
}

// ---------------------------------------------------------------------------
// K6: sequential SSM scan fused with y = einsum('bldn,bln->bld', clip(h), C)
// thread -> (b, d, n); 16 lanes per (b,d) reduce via shfl_xor.
// NOTE: running h is UNCLIPPED (reference clips only the h used for y).
// ---------------------------------------------------------------------------
__global__ __launch_bounds__(256) void k_scan(
    const float* __restrict__ dmod,    // (B*L, DI)
    const float* __restrict__ xact,    // (B*L, DI)
    const float* __restrict__ xdbl,    // (B*L, 80): [dt 48 | B 16 | C 16]
    const float* __restrict__ basenum, // (DI, NS)
    const int*   __restrict__ shifts,  // (DI, NS)
    float* __restrict__ y)             // (B*L, DI)
{
    int g = blockIdx.x * 256 + threadIdx.x;
    int n  = g & 15;
    int dd = (g >> 4) % DII;
    int b  = g / (16 * DII);
    float base = basenum[dd * NSS + n];
    float p2   = exp2f(-(float)shifts[dd * NSS + n]);
    float h = 0.f;
    for (int l = 0; l < LL; ++l) {
        int row = b * LL + l;
        float dm = dmod[(size_t)row * DII + dd];
        float xv = xact[(size_t)row * DII + dd];
        float Bv = xdbl[(size_t)row * XDN + DTRR + n];
        float Cv = xdbl[(size_t)row * XDN + DTRR + NSS + n];
        float a  = clampf(base + dm, 0.f, 32767.f) * p2;
        float u  = xv * (dspf(dm) * 0.1f) * Bv;
        h = fmaf(a, h, u);
        float hc = clampf(h, -32000.f, 32000.f);
        float p  = hc * Cv;
        p += __shfl_xor(p, 1);
        p += __shfl_xor(p, 2);
        p += __shfl_xor(p, 4);
        p += __shfl_xor(p, 8);
        if (n == 0) y[(size_t)row * DII + dd] = p;
    }
}

// ---------------------------------------------------------------------------
// K7: final GEMM with gate on A and residual epilogue.
// out[m,n] = resid[m,n] + clip(sum_k (y[m,k]*gate(z[m,k])) * Wout[n,k] + bout[n]) * rg
// ---------------------------------------------------------------------------
__global__ __launch_bounds__(256) void k_gemm_out(
    const float* __restrict__ Yv,     // (2048, DI)
    const float* __restrict__ xz,     // (2048, 3072), z at col DI+k
    const float* __restrict__ Wout,   // (DM, DI)
    const float* __restrict__ bout,
    const float* __restrict__ resid,  // (2048, DM)
    const float* __restrict__ rgate,  // scalar
    float* __restrict__ out)
{
    const int TS = 64, KS = 16;
    __shared__ float As[KS][TS + 4];
    __shared__ float Bs[KS][TS + 4];
    int bm = blockIdx.y * TS, bn = blockIdx.x * TS;
    int tid = threadIdx.x;
    int tx = tid & 15, ty = tid >> 4;
    float acc[4][4] = {{0.f}};

    for (int k0 = 0; k0 < DII; k0 += KS) {
        for (int i = tid; i < TS * KS; i += 256) {
            int c = i & (KS - 1), r = i >> 4;
            int gr = bm + r, gc = k0 + c;
            float yv = Yv[(size_t)gr * DII + gc];
            float z  = xz[(size_t)gr * XZN + DII + gc];
            float gate = 0.5f * (1.0f + z / sqrtf(z * z + 1.0f));
            As[c][r] = yv * gate;
        }
        for (int i = tid; i < TS * KS; i += 256) {
            int c = i & (KS - 1), r = i >> 4;
            int gr = bn + r, gc = k0 + c;
            Bs[c][r] = Wout[(size_t)gr * DII + gc];
        }
        __syncthreads();
        #pragma unroll
        for (int k = 0; k < KS; ++k) {
            const float4 av = *reinterpret_cast<const float4*>(&As[k][ty * 4]);
            const float4 bv = *reinterpret_cast<const float4*>(&Bs[k][tx * 4]);
            const float a0[4] = {av.x, av.y, av.z, av.w};
            const float b0[4] = {bv.x, bv.y, bv.z, bv.w};
            #pragma unroll
            for (int i = 0; i < 4; ++i)
                #pragma unroll
                for (int j = 0; j < 4; ++j)
                    acc[i][j] = fmaf(a0[i], b0[j], acc[i][j]);
        }
        __syncthreads();
    }
    float rg = rgate[0];
    #pragma unroll
    for (int i = 0; i < 4; ++i)
        #pragma unroll
        for (int j = 0; j < 4; ++j) {
            int gr = bm + ty * 4 + i, gc = bn + tx * 4 + j;
            float o = acc[i][j] + bout[gc];
            o = clampf(o, -32000.f, 32000.f);
            out[(size_t)gr * DMM + gc] = resid[(size_t)gr * DMM + gc] + o * rg;
        }
}

// ---------------------------------------------------------------------------
extern "C" void kernel_launch(void* const* d_in, const int* in_sizes, int n_in,
                              void* d_out, int out_size, void* d_ws, size_t ws_size,
                              hipStream_t stream) {
    const float* hs        = (const float*)d_in[0];
    const float* gamma     = (const float*)d_in[1];
    const float* W_in      = (const float*)d_in[2];
    const float* b_in      = (const float*)d_in[3];
    const float* conv_w    = (const float*)d_in[4];
    const float* conv_b    = (const float*)d_in[5];
    const float* W_x       = (const float*)d_in[6];
    const float* b_x       = (const float*)d_in[7];
    const float* W_dt      = (const float*)d_in[8];
    const float* b_dt      = (const float*)d_in[9];
    const float* W_out     = (const float*)d_in[10];
    const float* b_out     = (const float*)d_in[11];
    const float* base_dec  = (const float*)d_in[12];
    const float* res_gate  = (const float*)d_in[13];
    const int*   dec_shift = (const int*)d_in[14];

    float* ws = (float*)d_ws;
    // workspace layout (floats)
    float* XZ   = ws;                               // 2048*3072
    float* XACT = XZ   + (size_t)NROWS * XZN;       // 2048*1536
    float* XDBL = XACT + (size_t)NROWS * DII;       // 2048*80
    float* DMOD = XDBL + (size_t)NROWS * XDN;       // 2048*1536
    float* Y    = DMOD + (size_t)NROWS * DII;       // 2048*1536
    float* HSN  = Y    + (size_t)NROWS * DII;       // 2048*768

    float* out = (float*)d_out;

    // 1. norm
    k_norm<<<NROWS, 256, 0, stream>>>(hs, gamma, HSN);

    // 2. xz = hsn @ W_in^T + b_in    (2048 x 3072 x 768)
    k_gemm_tn<<<dim3(XZN / 64, NROWS / 64), 256, 0, stream>>>(
        HSN, DMM, W_in, DMM, b_in, XZ, XZN, NROWS, XZN, DMM);

    // 3. depthwise conv + dsp
    k_conv<<<(NROWS * DII) / 256, 256, 0, stream>>>(XZ, conv_w, conv_b, XACT);

    // 4. x_dbl = xact @ W_x^T + b_x  (2048 x 80 x 1536)
    k_gemm_tn<<<dim3((XDN + 63) / 64, NROWS / 64), 256, 0, stream>>>(
        XACT, DII, W_x, DII, b_x, XDBL, XDN, NROWS, XDN, DII);

    // 5. decay_mod = dt @ W_dt^T + b_dt  (2048 x 1536 x 48); dt = xdbl[:, :48]
    k_gemm_tn<<<dim3(DII / 64, NROWS / 64), 256, 0, stream>>>(
        XDBL, XDN, W_dt, DTRR, b_dt, DMOD, DII, NROWS, DII, DTRR);

    // 6. fused scan + einsum -> y
    k_scan<<<(BB * DII * NSS) / 256, 256, 0, stream>>>(
        DMOD, XACT, XDBL, base_dec, dec_shift, Y);

    // 7. final gemm: gate(z)*y @ W_out^T + b_out, clip, residual
    k_gemm_out<<<dim3(DMM / 64, NROWS / 64), 256, 0, stream>>>(
        Y, XZ, W_out, b_out, hs, res_gate, out);
}

// Round 2
// 777.695 us; speedup vs baseline: 1.4878x; 1.4878x over previous
//
#include <hip/hip_runtime.h>
#include <hip/hip_bf16.h>

// Problem constants
#define BB  2
#define LL  1024
#define DMM 768
#define DII 1536
#define NSS 16
#define DTRR 48
#define XZN (2*DII)        // 3072
#define XDN (DTRR+2*NSS)   // 80
#define NROWS (BB*LL)      // 2048

// chunked scan
#define CHUNKS 16
#define CHLEN  (LL/CHUNKS)          // 64
#define NCH    (BB*DII*NSS)         // 49152 independent channels

__device__ __forceinline__ float dspf(float x) {
    return 0.25f * (x + sqrtf(x*x + 4.0f));
}
__device__ __forceinline__ float clampf(float x, float lo, float hi) {
    return fminf(fmaxf(x, lo), hi);
}

// ---------------------------------------------------------------------------
// K1: norm.  one block per row (B*L rows of DM)
// ---------------------------------------------------------------------------
__global__ __launch_bounds__(256) void k_norm(const float* __restrict__ hs,
                                              const float* __restrict__ gamma,
                                              float* __restrict__ out) {
    int row = blockIdx.x;
    const float* p = hs + (size_t)row * DMM;
    __shared__ float red[256];
    int tid = threadIdx.x;

    float s = 0.f;
    for (int i = tid; i < DMM; i += 256) s += p[i];
    red[tid] = s; __syncthreads();
    for (int off = 128; off > 0; off >>= 1) {
        if (tid < off) red[tid] += red[tid + off];
        __syncthreads();
    }
    float mean = red[0] / (float)DMM;
    __syncthreads();

    float v = 0.f;
    for (int i = tid; i < DMM; i += 256) { float d = p[i] - mean; v += d*d; }
    red[tid] = v; __syncthreads();
    for (int off = 128; off > 0; off >>= 1) {
        if (tid < off) red[tid] += red[tid + off];
        __syncthreads();
    }
    float var = red[0] / (float)DMM;
    float k = rintf(log2f(sqrtf(var + 1e-9f)));   // round-half-even like jnp.round
    k = fmaxf(k, 0.f);
    float scale = exp2f(-k);
    for (int i = tid; i < DMM; i += 256)
        out[(size_t)row * DMM + i] = (p[i] - mean) * scale * gamma[i];
}

// ---------------------------------------------------------------------------
// Generic tiled fp32 GEMM:  C[M,N] = A[M,K] * B[N,K]^T + bias[N]
// 64x64 tile, KS=16, 256 threads, 4x4 per thread. K-major LDS => float4 reads.
// ---------------------------------------------------------------------------
__global__ __launch_bounds__(256) void k_gemm_tn(
    const float* __restrict__ A, int lda,
    const float* __restrict__ Bw, int ldb,
    const float* __restrict__ bias,
    float* __restrict__ C, int ldc,
    int M, int N, int K)
{
    const int TS = 64, KS = 16;
    __shared__ float As[KS][TS + 4];
    __shared__ float Bs[KS][TS + 4];
    int bm = blockIdx.y * TS, bn = blockIdx.x * TS;
    int tid = threadIdx.x;
    int tx = tid & 15, ty = tid >> 4;
    float acc[4][4] = {{0.f}};

    for (int k0 = 0; k0 < K; k0 += KS) {
        for (int i = tid; i < TS * KS; i += 256) {
            int c = i & (KS - 1), r = i >> 4;
            int gr = bm + r, gc = k0 + c;
            As[c][r] = (gr < M && gc < K) ? A[(size_t)gr * lda + gc] : 0.f;
        }
        for (int i = tid; i < TS * KS; i += 256) {
            int c = i & (KS - 1), r = i >> 4;
            int gr = bn + r, gc = k0 + c;
            Bs[c][r] = (gr < N && gc < K) ? Bw[(size_t)gr * ldb + gc] : 0.f;
        }
        __syncthreads();
        #pragma unroll
        for (int k = 0; k < KS; ++k) {
            const float4 av = *reinterpret_cast<const float4*>(&As[k][ty * 4]);
            const float4 bv = *reinterpret_cast<const float4*>(&Bs[k][tx * 4]);
            const float a0[4] = {av.x, av.y, av.z, av.w};
            const float b0[4] = {bv.x, bv.y, bv.z, bv.w};
            #pragma unroll
            for (int i = 0; i < 4; ++i)
                #pragma unroll
                for (int j = 0; j < 4; ++j)
                    acc[i][j] = fmaf(a0[i], b0[j], acc[i][j]);
        }
        __syncthreads();
    }
    #pragma unroll
    for (int i = 0; i < 4; ++i)
        #pragma unroll
        for (int j = 0; j < 4; ++j) {
            int gr = bm + ty * 4 + i, gc = bn + tx * 4 + j;
            if (gr < M && gc < N)
                C[(size_t)gr * ldc + gc] = acc[i][j] + bias[gc];
        }
}

// ---------------------------------------------------------------------------
// K3: depthwise causal conv (k=4, left pad 3) + dsp activation
// ---------------------------------------------------------------------------
__global__ __launch_bounds__(256) void k_conv(const float* __restrict__ xz,
                                              const float* __restrict__ cw,
                                              const float* __restrict__ cb,
                                              float* __restrict__ xact)
{
    int idx = blockIdx.x * 256 + threadIdx.x;       // over B*L*DI
    if (idx >= NROWS * DII) return;
    int c = idx % DII;
    int bl = idx / DII;
    int l = bl % LL;
    int b = bl / LL;
    float acc = cb[c];
    #pragma unroll
    for (int j = 0; j < 4; ++j) {
        int ls = l - 3 + j;
        if (ls >= 0)
            acc = fmaf(xz[(size_t)(b * LL + ls) * XZN + c], cw[c * 4 + j], acc);
    }
    xact[idx] = dspf(acc);
}

// ---------------------------------------------------------------------------
// Chunked parallel scan, 3 phases. channel ch = (b*DI + d)*NS + n,
// global index g = chunk*NCH + ch (consecutive tid -> consecutive ch).
// State buffer st[g] = (A = prod a over chunk, h_end local) written by P1;
// P2 overwrites st[g].x with the incoming prefix h_in; P3 replays chunk with
// h_in and emits y via 16-lane shfl reduce over n.
// Running h is UNCLIPPED (reference clips only the h used for y).
// ---------------------------------------------------------------------------
__global__ __launch_bounds__(256) void k_scan_p1(
    const float* __restrict__ dmod,    // (B*L, DI)
    const float* __restrict__ xact,    // (B*L, DI)
    const float* __restrict__ xdbl,    // (B*L, 80): [dt 48 | B 16 | C 16]
    const float* __restrict__ basenum, // (DI, NS)
    const int*   __restrict__ shifts,  // (DI, NS)
    float2* __restrict__ st)
{
    int g = blockIdx.x * 256 + threadIdx.x;
    int ch = g % NCH;
    int chunk = g / NCH;
    int n = ch & 15;
    int d = (ch >> 4) % DII;
    int b = ch / (DII * NSS);
    float base = basenum[d * NSS + n];
    float p2   = exp2f(-(float)shifts[d * NSS + n]);
    float h = 0.f, A = 1.f;
    int row0 = b * LL + chunk * CHLEN;
    #pragma unroll 4
    for (int l = 0; l < CHLEN; ++l) {
        int row = row0 + l;
        float dm = dmod[(size_t)row * DII + d];
        float xv = xact[(size_t)row * DII + d];
        float Bv = xdbl[(size_t)row * XDN + DTRR + n];
        float a  = clampf(base + dm, 0.f, 32767.f) * p2;
        float u  = xv * (dspf(dm) * 0.1f) * Bv;
        h = fmaf(a, h, u);
        A *= a;
    }
    st[g] = make_float2(A, h);
}

__global__ __launch_bounds__(256) void k_scan_p2(float2* __restrict__ st)
{
    int ch = blockIdx.x * 256 + threadIdx.x;   // [0, NCH)
    float hin = 0.f;
    #pragma unroll
    for (int c = 0; c < CHUNKS; ++c) {
        float2 s = st[(size_t)c * NCH + ch];
        st[(size_t)c * NCH + ch].x = hin;      // A slot -> h_in prefix
        hin = fmaf(s.x, hin, s.y);
    }
}

__global__ __launch_bounds__(256) void k_scan_p3(
    const float* __restrict__ dmod,
    const float* __restrict__ xact,
    const float* __restrict__ xdbl,
    const float* __restrict__ basenum,
    const int*   __restrict__ shifts,
    const float2* __restrict__ st,
    float* __restrict__ y)             // (B*L, DI)
{
    int g = blockIdx.x * 256 + threadIdx.x;
    int ch = g % NCH;
    int chunk = g / NCH;
    int n = ch & 15;
    int d = (ch >> 4) % DII;
    int b = ch / (DII * NSS);
    float base = basenum[d * NSS + n];
    float p2   = exp2f(-(float)shifts[d * NSS + n]);
    float h = st[g].x;                 // incoming prefix
    int row0 = b * LL + chunk * CHLEN;
    #pragma unroll 4
    for (int l = 0; l < CHLEN; ++l) {
        int row = row0 + l;
        float dm = dmod[(size_t)row * DII + d];
        float xv = xact[(size_t)row * DII + d];
        float Bv = xdbl[(size_t)row * XDN + DTRR + n];
        float Cv = xdbl[(size_t)row * XDN + DTRR + NSS + n];
        float a  = clampf(base + dm, 0.f, 32767.f) * p2;
        float u  = xv * (dspf(dm) * 0.1f) * Bv;
        h = fmaf(a, h, u);
        float hc = clampf(h, -32000.f, 32000.f);
        float p  = hc * Cv;
        p += __shfl_xor(p, 1);
        p += __shfl_xor(p, 2);
        p += __shfl_xor(p, 4);
        p += __shfl_xor(p, 8);
        if (n == 0) y[(size_t)row * DII + d] = p;
    }
}

// ---------------------------------------------------------------------------
// K7: final GEMM with gate on A and residual epilogue.
// ---------------------------------------------------------------------------
__global__ __launch_bounds__(256) void k_gemm_out(
    const float* __restrict__ Yv,     // (2048, DI)
    const float* __restrict__ xz,     // (2048, 3072), z at col DI+k
    const float* __restrict__ Wout,   // (DM, DI)
    const float* __restrict__ bout,
    const float* __restrict__ resid,  // (2048, DM)
    const float* __restrict__ rgate,  // scalar
    float* __restrict__ out)
{
    const int TS = 64, KS = 16;
    __shared__ float As[KS][TS + 4];
    __shared__ float Bs[KS][TS + 4];
    int bm = blockIdx.y * TS, bn = blockIdx.x * TS;
    int tid = threadIdx.x;
    int tx = tid & 15, ty = tid >> 4;
    float acc[4][4] = {{0.f}};

    for (int k0 = 0; k0 < DII; k0 += KS) {
        for (int i = tid; i < TS * KS; i += 256) {
            int c = i & (KS - 1), r = i >> 4;
            int gr = bm + r, gc = k0 + c;
            float yv = Yv[(size_t)gr * DII + gc];
            float z  = xz[(size_t)gr * XZN + DII + gc];
            float gate = 0.5f * (1.0f + z / sqrtf(z * z + 1.0f));
            As[c][r] = yv * gate;
        }
        for (int i = tid; i < TS * KS; i += 256) {
            int c = i & (KS - 1), r = i >> 4;
            int gr = bn + r, gc = k0 + c;
            Bs[c][r] = Wout[(size_t)gr * DII + gc];
        }
        __syncthreads();
        #pragma unroll
        for (int k = 0; k < KS; ++k) {
            const float4 av = *reinterpret_cast<const float4*>(&As[k][ty * 4]);
            const float4 bv = *reinterpret_cast<const float4*>(&Bs[k][tx * 4]);
            const float a0[4] = {av.x, av.y, av.z, av.w};
            const float b0[4] = {bv.x, bv.y, bv.z, bv.w};
            #pragma unroll
            for (int i = 0; i < 4; ++i)
                #pragma unroll
                for (int j = 0; j < 4; ++j)
                    acc[i][j] = fmaf(a0[i], b0[j], acc[i][j]);
        }
        __syncthreads();
    }
    float rg = rgate[0];
    #pragma unroll
    for (int i = 0; i < 4; ++i)
        #pragma unroll
        for (int j = 0; j < 4; ++j) {
            int gr = bm + ty * 4 + i, gc = bn + tx * 4 + j;
            float o = acc[i][j] + bout[gc];
            o = clampf(o, -32000.f, 32000.f);
            out[(size_t)gr * DMM + gc] = resid[(size_t)gr * DMM + gc] + o * rg;
        }
}

// ---------------------------------------------------------------------------
extern "C" void kernel_launch(void* const* d_in, const int* in_sizes, int n_in,
                              void* d_out, int out_size, void* d_ws, size_t ws_size,
                              hipStream_t stream) {
    const float* hs        = (const float*)d_in[0];
    const float* gamma     = (const float*)d_in[1];
    const float* W_in      = (const float*)d_in[2];
    const float* b_in      = (const float*)d_in[3];
    const float* conv_w    = (const float*)d_in[4];
    const float* conv_b    = (const float*)d_in[5];
    const float* W_x       = (const float*)d_in[6];
    const float* b_x       = (const float*)d_in[7];
    const float* W_dt      = (const float*)d_in[8];
    const float* b_dt      = (const float*)d_in[9];
    const float* W_out     = (const float*)d_in[10];
    const float* b_out     = (const float*)d_in[11];
    const float* base_dec  = (const float*)d_in[12];
    const float* res_gate  = (const float*)d_in[13];
    const int*   dec_shift = (const int*)d_in[14];

    float* ws = (float*)d_ws;
    // workspace layout (floats)
    float* XZ   = ws;                               // 2048*3072
    float* XACT = XZ   + (size_t)NROWS * XZN;       // 2048*1536
    float* XDBL = XACT + (size_t)NROWS * DII;       // 2048*80
    float* DMOD = XDBL + (size_t)NROWS * XDN;       // 2048*1536
    float* Y    = DMOD + (size_t)NROWS * DII;       // 2048*1536
    float* HSN  = Y    + (size_t)NROWS * DII;       // 2048*768
    // scan chunk states reuse HSN region (dead after GEMM1):
    // CHUNKS*NCH float2 = 786432*2 floats = 1572864 floats = exactly HSN size
    float2* SCST = (float2*)HSN;

    float* out = (float*)d_out;

    // 1. norm
    k_norm<<<NROWS, 256, 0, stream>>>(hs, gamma, HSN);

    // 2. xz = hsn @ W_in^T + b_in    (2048 x 3072 x 768)
    k_gemm_tn<<<dim3(XZN / 64, NROWS / 64), 256, 0, stream>>>(
        HSN, DMM, W_in, DMM, b_in, XZ, XZN, NROWS, XZN, DMM);

    // 3. depthwise conv + dsp
    k_conv<<<(NROWS * DII) / 256, 256, 0, stream>>>(XZ, conv_w, conv_b, XACT);

    // 4. x_dbl = xact @ W_x^T + b_x  (2048 x 80 x 1536)
    k_gemm_tn<<<dim3((XDN + 63) / 64, NROWS / 64), 256, 0, stream>>>(
        XACT, DII, W_x, DII, b_x, XDBL, XDN, NROWS, XDN, DII);

    // 5. decay_mod = dt @ W_dt^T + b_dt  (2048 x 1536 x 48)
    k_gemm_tn<<<dim3(DII / 64, NROWS / 64), 256, 0, stream>>>(
        XDBL, XDN, W_dt, DTRR, b_dt, DMOD, DII, NROWS, DII, DTRR);

    // 6. chunked scan (3 phases) + fused einsum -> y
    k_scan_p1<<<(CHUNKS * NCH) / 256, 256, 0, stream>>>(
        DMOD, XACT, XDBL, base_dec, dec_shift, SCST);
    k_scan_p2<<<NCH / 256, 256, 0, stream>>>(SCST);
    k_scan_p3<<<(CHUNKS * NCH) / 256, 256, 0, stream>>>(
        DMOD, XACT, XDBL, base_dec, dec_shift, SCST, Y);

    // 7. final gemm: gate(z)*y @ W_out^T + b_out, clip, residual
    k_gemm_out<<<dim3(DMM / 64, NROWS / 64), 256, 0, stream>>>(
        Y, XZ, W_out, b_out, hs, res_gate, out);
}

// Round 3
// 312.379 us; speedup vs baseline: 3.7040x; 2.4896x over previous
//
#include <hip/hip_runtime.h>
#include <hip/hip_bf16.h>
#include <stdint.h>

// Problem constants
#define BB  2
#define LL  1024
#define DMM 768
#define DII 1536
#define NSS 16
#define DTRR 48
#define XZN (2*DII)        // 3072
#define NROWS (BB*LL)      // 2048
#define N2 1664            // padded N for combined GEMM2 (1536 dmod + 32 B/C + 96 pad)

// chunked scan
#define CHUNKS 16
#define CHLEN  (LL/CHUNKS)          // 64
#define NCH    (BB*DII*NSS)         // 49152

typedef _Float16 h16;
typedef __attribute__((ext_vector_type(8))) _Float16 h16x8;
typedef __attribute__((ext_vector_type(4))) float f32x4;

typedef const __attribute__((address_space(1))) uint32_t gau32;
typedef __attribute__((address_space(3))) uint32_t lau32;
#define GLL16(gp, lp) __builtin_amdgcn_global_load_lds((gau32*)(gp), (lau32*)(lp), 16, 0, 0)

__device__ __forceinline__ float dspf(float x) {
    return 0.25f * (x + sqrtf(x*x + 4.0f));
}
__device__ __forceinline__ float clampf(float x, float lo, float hi) {
    return fminf(fmaxf(x, lo), hi);
}

// ---------------------------------------------------------------------------
// f32 -> f16 convert
// ---------------------------------------------------------------------------
__global__ __launch_bounds__(256) void k_cvt(const float* __restrict__ in,
                                             h16* __restrict__ out, int n) {
    int i = blockIdx.x * 256 + threadIdx.x;
    if (i < n) out[i] = (h16)in[i];
}

// ---------------------------------------------------------------------------
// Build combined W2 [N2 x DII] (f16) + bias2 [N2] (f32):
//  rows 0..1535   : (W_dt @ W_x[:48]) row i   ; bias b_dt[i] + W_dt[i]·b_x[:48]
//  rows 1536..1567: W_x[48 + r]               ; bias b_x[48+r]
//  rows 1568..    : 0                          ; bias 0
// ---------------------------------------------------------------------------
__global__ __launch_bounds__(256) void k_w2(const float* __restrict__ W_x,
                                            const float* __restrict__ b_x,
                                            const float* __restrict__ W_dt,
                                            const float* __restrict__ b_dt,
                                            h16* __restrict__ W2,
                                            float* __restrict__ bias2) {
    int i = blockIdx.x;
    int tid = threadIdx.x;
    if (i < DII) {
        __shared__ float wd[DTRR];
        if (tid < DTRR) wd[tid] = W_dt[i * DTRR + tid];
        __syncthreads();
        for (int j = tid; j < DII; j += 256) {
            float s = 0.f;
            #pragma unroll
            for (int k = 0; k < DTRR; ++k) s = fmaf(wd[k], W_x[(size_t)k * DII + j], s);
            W2[(size_t)i * DII + j] = (h16)s;
        }
        if (tid == 0) {
            float s = b_dt[i];
            for (int k = 0; k < DTRR; ++k) s = fmaf(wd[k], b_x[k], s);
            bias2[i] = s;
        }
    } else if (i < DII + 2 * NSS) {
        int r = i - DII;
        for (int j = tid; j < DII; j += 256)
            W2[(size_t)i * DII + j] = (h16)W_x[(size_t)(DTRR + r) * DII + j];
        if (tid == 0) bias2[i] = b_x[DTRR + r];
    } else {
        for (int j = tid; j < DII; j += 256) W2[(size_t)i * DII + j] = (h16)0.f;
        if (tid == 0) bias2[i] = 0.f;
    }
}

// ---------------------------------------------------------------------------
// K1: norm -> f16 output (feeds MFMA GEMM1 only)
// ---------------------------------------------------------------------------
__global__ __launch_bounds__(256) void k_norm(const float* __restrict__ hs,
                                              const float* __restrict__ gamma,
                                              h16* __restrict__ out) {
    int row = blockIdx.x;
    const float* p = hs + (size_t)row * DMM;
    __shared__ float red[256];
    int tid = threadIdx.x;

    float s = 0.f;
    for (int i = tid; i < DMM; i += 256) s += p[i];
    red[tid] = s; __syncthreads();
    for (int off = 128; off > 0; off >>= 1) {
        if (tid < off) red[tid] += red[tid + off];
        __syncthreads();
    }
    float mean = red[0] / (float)DMM;
    __syncthreads();

    float v = 0.f;
    for (int i = tid; i < DMM; i += 256) { float d = p[i] - mean; v += d*d; }
    red[tid] = v; __syncthreads();
    for (int off = 128; off > 0; off >>= 1) {
        if (tid < off) red[tid] += red[tid + off];
        __syncthreads();
    }
    float var = red[0] / (float)DMM;
    float k = rintf(log2f(sqrtf(var + 1e-9f)));
    k = fmaxf(k, 0.f);
    float scale = exp2f(-k);
    for (int i = tid; i < DMM; i += 256)
        out[(size_t)row * DMM + i] = (h16)((p[i] - mean) * scale * gamma[i]);
}

// ---------------------------------------------------------------------------
// MFMA f16 GEMM: C[M,N] = A[M,K](f16) * B[N,K]^T(f16) + bias[N]
// 128x128 tile, BK=64, 4 waves (each 64x64), 16x16x32_f16 MFMA.
// global_load_lds(16B) with pre-swizzled source; XOR swizzle (blk ^ row&7)
// on ds_read -> conflict-free. Dims must be multiples of 128 (M,N) / 64 (K).
// EPI==1: out = resid + clip(acc+bias,±32000)*rg
// ---------------------------------------------------------------------------
template<int EPI>
__global__ __launch_bounds__(256) void k_gemm_h(
    const h16* __restrict__ A, int lda,
    const h16* __restrict__ Bw, int ldb,
    const float* __restrict__ bias,
    float* __restrict__ C, int ldc, int K,
    const float* __restrict__ resid, const float* __restrict__ rgate)
{
    __shared__ __align__(16) h16 As[128 * 64];
    __shared__ __align__(16) h16 Bs[128 * 64];
    const int tid  = threadIdx.x;
    const int lane = tid & 63;
    const int wv   = tid >> 6;
    const int bm = blockIdx.y * 128, bn = blockIdx.x * 128;
    const int wr = wv >> 1, wc = wv & 1;

    f32x4 acc[4][4] = {};

    // staging: per issue q, wave wv covers rows (wv*4+q)*8 .. +7 (row = 128B)
    const int srow = lane >> 3;                    // row within 8-row issue
    const int kbl  = ((lane & 7) ^ srow) * 8;      // pre-swizzled logical k-block

    for (int k0 = 0; k0 < K; k0 += 64) {
        __syncthreads();                           // all reads of prev tile done
        #pragma unroll
        for (int q = 0; q < 4; ++q) {
            int row = (wv * 4 + q) * 8 + srow;
            GLL16(A  + (size_t)(bm + row) * lda + k0 + kbl, &As[(size_t)((wv*4+q)*8) * 64]);
            GLL16(Bw + (size_t)(bn + row) * ldb + k0 + kbl, &Bs[(size_t)((wv*4+q)*8) * 64]);
        }
        asm volatile("s_waitcnt vmcnt(0)" ::: "memory");
        __syncthreads();                           // tile visible to all

        const int r16 = lane & 15, kq = lane >> 4;
        #pragma unroll
        for (int kk = 0; kk < 2; ++kk) {
            h16x8 af[4], bf[4];
            #pragma unroll
            for (int i = 0; i < 4; ++i) {
                int rowA = wr * 64 + i * 16 + r16;
                af[i] = *(const h16x8*)&As[rowA * 64 + (((kk*4 + kq) ^ (rowA & 7)) << 3)];
            }
            #pragma unroll
            for (int j = 0; j < 4; ++j) {
                int rowB = wc * 64 + j * 16 + r16;
                bf[j] = *(const h16x8*)&Bs[rowB * 64 + (((kk*4 + kq) ^ (rowB & 7)) << 3)];
            }
            #pragma unroll
            for (int i = 0; i < 4; ++i)
                #pragma unroll
                for (int j = 0; j < 4; ++j)
                    acc[i][j] = __builtin_amdgcn_mfma_f32_16x16x32_f16(af[i], bf[j], acc[i][j], 0, 0, 0);
        }
    }

    // epilogue: C layout col = lane&15, row = (lane>>4)*4 + reg
    const int r4 = (lane >> 4) * 4;
    const int cn = lane & 15;
    float rg = 0.f;
    if (EPI) rg = rgate[0];
    #pragma unroll
    for (int i = 0; i < 4; ++i) {
        #pragma unroll
        for (int j = 0; j < 4; ++j) {
            int col = bn + wc * 64 + j * 16 + cn;
            float bv = bias[col];
            #pragma unroll
            for (int r = 0; r < 4; ++r) {
                int row = bm + wr * 64 + i * 16 + r4 + r;
                float v = acc[i][j][r] + bv;
                if (EPI) {
                    v = clampf(v, -32000.f, 32000.f);
                    v = resid[(size_t)row * ldc + col] + v * rg;
                }
                C[(size_t)row * ldc + col] = v;
            }
        }
    }
}

// ---------------------------------------------------------------------------
// K3: depthwise causal conv (k=4, left pad 3) + dsp -> f16 output
// ---------------------------------------------------------------------------
__global__ __launch_bounds__(256) void k_conv(const float* __restrict__ xz,
                                              const float* __restrict__ cw,
                                              const float* __restrict__ cb,
                                              h16* __restrict__ xacth)
{
    int idx = blockIdx.x * 256 + threadIdx.x;       // over B*L*DI
    if (idx >= NROWS * DII) return;
    int c = idx % DII;
    int bl = idx / DII;
    int l = bl % LL;
    int b = bl / LL;
    float acc = cb[c];
    #pragma unroll
    for (int j = 0; j < 4; ++j) {
        int ls = l - 3 + j;
        if (ls >= 0)
            acc = fmaf(xz[(size_t)(b * LL + ls) * XZN + c], cw[c * 4 + j], acc);
    }
    xacth[idx] = (h16)dspf(acc);
}

// ---------------------------------------------------------------------------
// Chunked scan (3 phases). dmbc = combined GEMM2 output, ld N2:
//   cols [0,1536) = decay_mod, [1536,1552) = B_ssm, [1552,1568) = C_ssm
// ---------------------------------------------------------------------------
__global__ __launch_bounds__(256) void k_scan_p1(
    const float* __restrict__ dmbc,
    const h16*   __restrict__ xacth,
    const float* __restrict__ basenum,
    const int*   __restrict__ shifts,
    float2* __restrict__ st)
{
    int g = blockIdx.x * 256 + threadIdx.x;
    int ch = g % NCH;
    int chunk = g / NCH;
    int n = ch & 15;
    int d = (ch >> 4) % DII;
    int b = ch / (DII * NSS);
    float base = basenum[d * NSS + n];
    float p2   = exp2f(-(float)shifts[d * NSS + n]);
    float h = 0.f, Ap = 1.f;
    int row0 = b * LL + chunk * CHLEN;
    #pragma unroll 4
    for (int l = 0; l < CHLEN; ++l) {
        int row = row0 + l;
        float dm = dmbc[(size_t)row * N2 + d];
        float xv = (float)xacth[(size_t)row * DII + d];
        float Bv = dmbc[(size_t)row * N2 + DII + n];
        float a  = clampf(base + dm, 0.f, 32767.f) * p2;
        float u  = xv * (dspf(dm) * 0.1f) * Bv;
        h = fmaf(a, h, u);
        Ap *= a;
    }
    st[g] = make_float2(Ap, h);
}

__global__ __launch_bounds__(256) void k_scan_p2(float2* __restrict__ st)
{
    int ch = blockIdx.x * 256 + threadIdx.x;
    float hin = 0.f;
    #pragma unroll
    for (int c = 0; c < CHUNKS; ++c) {
        float2 s = st[(size_t)c * NCH + ch];
        st[(size_t)c * NCH + ch].x = hin;
        hin = fmaf(s.x, hin, s.y);
    }
}

__global__ __launch_bounds__(256) void k_scan_p3(
    const float* __restrict__ dmbc,
    const h16*   __restrict__ xacth,
    const float* __restrict__ xz,
    const float* __restrict__ basenum,
    const int*   __restrict__ shifts,
    const float2* __restrict__ st,
    h16* __restrict__ ygh)             // (B*L, DI) = y * gate(z), f16
{
    int g = blockIdx.x * 256 + threadIdx.x;
    int ch = g % NCH;
    int chunk = g / NCH;
    int n = ch & 15;
    int d = (ch >> 4) % DII;
    int b = ch / (DII * NSS);
    float base = basenum[d * NSS + n];
    float p2   = exp2f(-(float)shifts[d * NSS + n]);
    float h = st[g].x;
    int row0 = b * LL + chunk * CHLEN;
    #pragma unroll 4
    for (int l = 0; l < CHLEN; ++l) {
        int row = row0 + l;
        float dm = dmbc[(size_t)row * N2 + d];
        float xv = (float)xacth[(size_t)row * DII + d];
        float Bv = dmbc[(size_t)row * N2 + DII + n];
        float Cv = dmbc[(size_t)row * N2 + DII + NSS + n];
        float a  = clampf(base + dm, 0.f, 32767.f) * p2;
        float u  = xv * (dspf(dm) * 0.1f) * Bv;
        h = fmaf(a, h, u);
        float hc = clampf(h, -32000.f, 32000.f);
        float p  = hc * Cv;
        p += __shfl_xor(p, 1);
        p += __shfl_xor(p, 2);
        p += __shfl_xor(p, 4);
        p += __shfl_xor(p, 8);
        if (n == 0) {
            float z = xz[(size_t)row * XZN + DII + d];
            float gate = 0.5f * (1.0f + z / sqrtf(z * z + 1.0f));
            ygh[(size_t)row * DII + d] = (h16)(p * gate);
        }
    }
}

// ---------------------------------------------------------------------------
extern "C" void kernel_launch(void* const* d_in, const int* in_sizes, int n_in,
                              void* d_out, int out_size, void* d_ws, size_t ws_size,
                              hipStream_t stream) {
    const float* hs        = (const float*)d_in[0];
    const float* gamma     = (const float*)d_in[1];
    const float* W_in      = (const float*)d_in[2];
    const float* b_in      = (const float*)d_in[3];
    const float* conv_w    = (const float*)d_in[4];
    const float* conv_b    = (const float*)d_in[5];
    const float* W_x       = (const float*)d_in[6];
    const float* b_x       = (const float*)d_in[7];
    const float* W_dt      = (const float*)d_in[8];
    const float* b_dt      = (const float*)d_in[9];
    const float* W_out     = (const float*)d_in[10];
    const float* b_out     = (const float*)d_in[11];
    const float* base_dec  = (const float*)d_in[12];
    const float* res_gate  = (const float*)d_in[13];
    const int*   dec_shift = (const int*)d_in[14];

    // workspace layout (bytes)
    char* w = (char*)d_ws;
    float* XZ    = (float*)w;  w += (size_t)NROWS * XZN * 4;   // 25.2 MB
    h16*   XACTH = (h16*)w;    w += (size_t)NROWS * DII * 2;   //  6.3 MB
    float* DMBC  = (float*)w;  w += (size_t)NROWS * N2  * 4;   // 13.6 MB
    h16*   HSNH  = (h16*)w;    w += (size_t)NROWS * DMM * 2;   //  3.1 MB
    h16*   W2H   = (h16*)w;    w += (size_t)N2 * DII * 2;      //  5.1 MB
    h16*   WOH   = (h16*)w;    w += (size_t)DMM * DII * 2;     //  2.4 MB
    float* BIAS2 = (float*)w;  w += (size_t)N2 * 4;            //  6.7 KB
    h16*   YGH   = (h16*)w;    w += (size_t)NROWS * DII * 2;   //  6.3 MB
    // overlay region: WINH (4.7 MB, dead after gemm1) / SCST (6.3 MB, scan only)
    h16*    WINH = (h16*)w;
    float2* SCST = (float2*)w;

    float* out = (float*)d_out;

    // 0. weight prep
    k_cvt<<<(XZN * DMM + 255) / 256, 256, 0, stream>>>(W_in, WINH, XZN * DMM);
    k_cvt<<<(DMM * DII + 255) / 256, 256, 0, stream>>>(W_out, WOH, DMM * DII);
    k_w2<<<N2, 256, 0, stream>>>(W_x, b_x, W_dt, b_dt, W2H, BIAS2);

    // 1. norm -> f16
    k_norm<<<NROWS, 256, 0, stream>>>(hs, gamma, HSNH);

    // 2. xz = hsn @ W_in^T + b_in   (2048 x 3072 x 768), fp32 out
    k_gemm_h<0><<<dim3(XZN / 128, NROWS / 128), 256, 0, stream>>>(
        HSNH, DMM, WINH, DMM, b_in, XZ, XZN, DMM, nullptr, nullptr);

    // 3. conv + dsp -> f16
    k_conv<<<(NROWS * DII) / 256, 256, 0, stream>>>(XZ, conv_w, conv_b, XACTH);

    // 4. combined: [decay_mod | B | C] = xact @ W2^T + bias2  (2048 x 1664 x 1536)
    k_gemm_h<0><<<dim3(N2 / 128, NROWS / 128), 256, 0, stream>>>(
        XACTH, DII, W2H, DII, BIAS2, DMBC, N2, DII, nullptr, nullptr);

    // 5. chunked scan + fused einsum + gate -> ygh (f16)
    k_scan_p1<<<(CHUNKS * NCH) / 256, 256, 0, stream>>>(
        DMBC, XACTH, base_dec, dec_shift, SCST);
    k_scan_p2<<<NCH / 256, 256, 0, stream>>>(SCST);
    k_scan_p3<<<(CHUNKS * NCH) / 256, 256, 0, stream>>>(
        DMBC, XACTH, XZ, base_dec, dec_shift, SCST, YGH);

    // 6. out = resid + clip(yg @ W_out^T + b_out)*rg   (2048 x 768 x 1536)
    k_gemm_h<1><<<dim3(DMM / 128, NROWS / 128), 256, 0, stream>>>(
        YGH, DII, WOH, DII, b_out, out, DMM, DII, hs, res_gate);
}

// Round 4
// 203.445 us; speedup vs baseline: 5.6873x; 1.5355x over previous
//
#include <hip/hip_runtime.h>
#include <hip/hip_bf16.h>
#include <stdint.h>

// Problem constants
#define BB  2
#define LL  1024
#define DMM 768
#define DII 1536
#define NSS 16
#define DTRR 48
#define XZN (2*DII)        // 3072
#define NROWS (BB*LL)      // 2048
#define N2 1664            // padded N for combined GEMM2 (1536 dmod + 32 B/C + 96 pad)

// chunked scan: one thread per (b, d, chunk), 16 n-states in registers
#define CHUNKS 64
#define CHLEN  (LL/CHUNKS)          // 16
#define NCH    (BB*DII*NSS)         // 49152 channels for p2

typedef _Float16 h16;
typedef __attribute__((ext_vector_type(8))) _Float16 h16x8;
typedef __attribute__((ext_vector_type(4))) float f32x4;

typedef const __attribute__((address_space(1))) uint32_t gau32;
typedef __attribute__((address_space(3))) uint32_t lau32;
#define GLL16(gp, lp) __builtin_amdgcn_global_load_lds((gau32*)(gp), (lau32*)(lp), 16, 0, 0)

__device__ __forceinline__ float dspf(float x) {
    return 0.25f * (x + sqrtf(x*x + 4.0f));
}
__device__ __forceinline__ float clampf(float x, float lo, float hi) {
    return fminf(fmaxf(x, lo), hi);
}

// ---------------------------------------------------------------------------
// f32 -> f16 convert
// ---------------------------------------------------------------------------
__global__ __launch_bounds__(256) void k_cvt(const float* __restrict__ in,
                                             h16* __restrict__ out, int n) {
    int i = blockIdx.x * 256 + threadIdx.x;
    if (i < n) out[i] = (h16)in[i];
}

// ---------------------------------------------------------------------------
// Build combined W2 [N2 x DII] (f16) + bias2 [N2] (f32)
// ---------------------------------------------------------------------------
__global__ __launch_bounds__(256) void k_w2(const float* __restrict__ W_x,
                                            const float* __restrict__ b_x,
                                            const float* __restrict__ W_dt,
                                            const float* __restrict__ b_dt,
                                            h16* __restrict__ W2,
                                            float* __restrict__ bias2) {
    int i = blockIdx.x;
    int tid = threadIdx.x;
    if (i < DII) {
        __shared__ float wd[DTRR];
        if (tid < DTRR) wd[tid] = W_dt[i * DTRR + tid];
        __syncthreads();
        for (int j = tid; j < DII; j += 256) {
            float s = 0.f;
            #pragma unroll
            for (int k = 0; k < DTRR; ++k) s = fmaf(wd[k], W_x[(size_t)k * DII + j], s);
            W2[(size_t)i * DII + j] = (h16)s;
        }
        if (tid == 0) {
            float s = b_dt[i];
            for (int k = 0; k < DTRR; ++k) s = fmaf(wd[k], b_x[k], s);
            bias2[i] = s;
        }
    } else if (i < DII + 2 * NSS) {
        int r = i - DII;
        for (int j = tid; j < DII; j += 256)
            W2[(size_t)i * DII + j] = (h16)W_x[(size_t)(DTRR + r) * DII + j];
        if (tid == 0) bias2[i] = b_x[DTRR + r];
    } else {
        for (int j = tid; j < DII; j += 256) W2[(size_t)i * DII + j] = (h16)0.f;
        if (tid == 0) bias2[i] = 0.f;
    }
}

// ---------------------------------------------------------------------------
// K1: norm -> f16 output
// ---------------------------------------------------------------------------
__global__ __launch_bounds__(256) void k_norm(const float* __restrict__ hs,
                                              const float* __restrict__ gamma,
                                              h16* __restrict__ out) {
    int row = blockIdx.x;
    const float* p = hs + (size_t)row * DMM;
    __shared__ float red[256];
    int tid = threadIdx.x;

    float s = 0.f;
    for (int i = tid; i < DMM; i += 256) s += p[i];
    red[tid] = s; __syncthreads();
    for (int off = 128; off > 0; off >>= 1) {
        if (tid < off) red[tid] += red[tid + off];
        __syncthreads();
    }
    float mean = red[0] / (float)DMM;
    __syncthreads();

    float v = 0.f;
    for (int i = tid; i < DMM; i += 256) { float d = p[i] - mean; v += d*d; }
    red[tid] = v; __syncthreads();
    for (int off = 128; off > 0; off >>= 1) {
        if (tid < off) red[tid] += red[tid + off];
        __syncthreads();
    }
    float var = red[0] / (float)DMM;
    float k = rintf(log2f(sqrtf(var + 1e-9f)));
    k = fmaxf(k, 0.f);
    float scale = exp2f(-k);
    for (int i = tid; i < DMM; i += 256)
        out[(size_t)row * DMM + i] = (h16)((p[i] - mean) * scale * gamma[i]);
}

// ---------------------------------------------------------------------------
// MFMA f16 GEMM (unchanged from round 3)
// ---------------------------------------------------------------------------
template<int EPI>
__global__ __launch_bounds__(256) void k_gemm_h(
    const h16* __restrict__ A, int lda,
    const h16* __restrict__ Bw, int ldb,
    const float* __restrict__ bias,
    float* __restrict__ C, int ldc, int K,
    const float* __restrict__ resid, const float* __restrict__ rgate)
{
    __shared__ __align__(16) h16 As[128 * 64];
    __shared__ __align__(16) h16 Bs[128 * 64];
    const int tid  = threadIdx.x;
    const int lane = tid & 63;
    const int wv   = tid >> 6;
    const int bm = blockIdx.y * 128, bn = blockIdx.x * 128;
    const int wr = wv >> 1, wc = wv & 1;

    f32x4 acc[4][4] = {};

    const int srow = lane >> 3;                    // row within 8-row issue
    const int kbl  = ((lane & 7) ^ srow) * 8;      // pre-swizzled logical k-block

    for (int k0 = 0; k0 < K; k0 += 64) {
        __syncthreads();
        #pragma unroll
        for (int q = 0; q < 4; ++q) {
            int row = (wv * 4 + q) * 8 + srow;
            GLL16(A  + (size_t)(bm + row) * lda + k0 + kbl, &As[(size_t)((wv*4+q)*8) * 64]);
            GLL16(Bw + (size_t)(bn + row) * ldb + k0 + kbl, &Bs[(size_t)((wv*4+q)*8) * 64]);
        }
        asm volatile("s_waitcnt vmcnt(0)" ::: "memory");
        __syncthreads();

        const int r16 = lane & 15, kq = lane >> 4;
        #pragma unroll
        for (int kk = 0; kk < 2; ++kk) {
            h16x8 af[4], bf[4];
            #pragma unroll
            for (int i = 0; i < 4; ++i) {
                int rowA = wr * 64 + i * 16 + r16;
                af[i] = *(const h16x8*)&As[rowA * 64 + (((kk*4 + kq) ^ (rowA & 7)) << 3)];
            }
            #pragma unroll
            for (int j = 0; j < 4; ++j) {
                int rowB = wc * 64 + j * 16 + r16;
                bf[j] = *(const h16x8*)&Bs[rowB * 64 + (((kk*4 + kq) ^ (rowB & 7)) << 3)];
            }
            #pragma unroll
            for (int i = 0; i < 4; ++i)
                #pragma unroll
                for (int j = 0; j < 4; ++j)
                    acc[i][j] = __builtin_amdgcn_mfma_f32_16x16x32_f16(af[i], bf[j], acc[i][j], 0, 0, 0);
        }
    }

    const int r4 = (lane >> 4) * 4;
    const int cn = lane & 15;
    float rg = 0.f;
    if (EPI) rg = rgate[0];
    #pragma unroll
    for (int i = 0; i < 4; ++i) {
        #pragma unroll
        for (int j = 0; j < 4; ++j) {
            int col = bn + wc * 64 + j * 16 + cn;
            float bv = bias[col];
            #pragma unroll
            for (int r = 0; r < 4; ++r) {
                int row = bm + wr * 64 + i * 16 + r4 + r;
                float v = acc[i][j][r] + bv;
                if (EPI) {
                    v = clampf(v, -32000.f, 32000.f);
                    v = resid[(size_t)row * ldc + col] + v * rg;
                }
                C[(size_t)row * ldc + col] = v;
            }
        }
    }
}

// ---------------------------------------------------------------------------
// K3: depthwise causal conv + dsp -> f16 xact; also gate(z) -> f16
// After this kernel XZ is dead (scan state overlays it).
// ---------------------------------------------------------------------------
__global__ __launch_bounds__(256) void k_conv(const float* __restrict__ xz,
                                              const float* __restrict__ cw,
                                              const float* __restrict__ cb,
                                              h16* __restrict__ xacth,
                                              h16* __restrict__ gateh)
{
    int idx = blockIdx.x * 256 + threadIdx.x;       // over B*L*DI
    if (idx >= NROWS * DII) return;
    int c = idx % DII;
    int bl = idx / DII;
    int l = bl % LL;
    int b = bl / LL;
    float acc = cb[c];
    #pragma unroll
    for (int j = 0; j < 4; ++j) {
        int ls = l - 3 + j;
        if (ls >= 0)
            acc = fmaf(xz[(size_t)(b * LL + ls) * XZN + c], cw[c * 4 + j], acc);
    }
    xacth[idx] = (h16)dspf(acc);
    float z = xz[(size_t)bl * XZN + DII + c];
    gateh[idx] = (h16)(0.5f * (1.0f + z * rsqrtf(z * z + 1.0f)));
}

// ---------------------------------------------------------------------------
// Chunked scan. Thread = (b, chunk, d); 16 n-states in registers.
// grid: BB*CHUNKS*6 blocks of 256 (6 blocks span d=0..1535, uniform row).
// st layout: ((b*CHUNKS+chunk)*DII + d)*16 + n  (float2: A-product, h-end;
// p2 rewrites .x to the incoming prefix h_in).
// ---------------------------------------------------------------------------
__global__ __launch_bounds__(256) void k_scan_p1(
    const float* __restrict__ dmbc,    // (B*L, N2): [dmod 1536 | B 16 | C 16 | pad]
    const h16*   __restrict__ xacth,   // (B*L, DI)
    const float* __restrict__ basenum, // (DI, NS)
    const int*   __restrict__ shifts,  // (DI, NS)
    float2* __restrict__ st)
{
    int bc   = blockIdx.x / 6;              // b*CHUNKS + chunk  (uniform)
    int dblk = blockIdx.x % 6;
    int d    = dblk * 256 + threadIdx.x;
    int b    = bc / CHUNKS;
    int chunk= bc % CHUNKS;

    float base[16], p2[16], h[16], A[16];
    #pragma unroll
    for (int n = 0; n < 16; ++n) {
        base[n] = basenum[d * NSS + n];
        p2[n]   = exp2f(-(float)shifts[d * NSS + n]);
        h[n] = 0.f; A[n] = 1.f;
    }
    int row0 = b * LL + chunk * CHLEN;
    #pragma unroll 2
    for (int l = 0; l < CHLEN; ++l) {
        int row = row0 + l;
        float dm = dmbc[(size_t)row * N2 + d];
        float xv = (float)xacth[(size_t)row * DII + d];
        float common = xv * (dspf(dm) * 0.1f);
        const float4* Bp = (const float4*)(dmbc + (size_t)row * N2 + DII);
        float4 B0 = Bp[0], B1 = Bp[1], B2 = Bp[2], B3 = Bp[3];
        const float Bv[16] = {B0.x,B0.y,B0.z,B0.w, B1.x,B1.y,B1.z,B1.w,
                              B2.x,B2.y,B2.z,B2.w, B3.x,B3.y,B3.z,B3.w};
        #pragma unroll
        for (int n = 0; n < 16; ++n) {
            float a = clampf(base[n] + dm, 0.f, 32767.f) * p2[n];
            h[n] = fmaf(a, h[n], common * Bv[n]);
            A[n] *= a;
        }
    }
    size_t sb = ((size_t)bc * DII + d) * 16;
    #pragma unroll
    for (int n = 0; n < 16; ++n) st[sb + n] = make_float2(A[n], h[n]);
}

__global__ __launch_bounds__(256) void k_scan_p2(float2* __restrict__ st)
{
    int ch = blockIdx.x * 256 + threadIdx.x;   // b*(DII*NSS) + d*16 + n
    int b  = ch / (DII * NSS);
    int rem = ch - b * (DII * NSS);
    float hin = 0.f;
    #pragma unroll 4
    for (int c = 0; c < CHUNKS; ++c) {
        size_t idx = ((size_t)(b * CHUNKS + c) * (DII * NSS)) + rem;
        float2 s = st[idx];
        st[idx].x = hin;
        hin = fmaf(s.x, hin, s.y);
    }
}

__global__ __launch_bounds__(256) void k_scan_p3(
    const float* __restrict__ dmbc,
    const h16*   __restrict__ xacth,
    const h16*   __restrict__ gateh,
    const float* __restrict__ basenum,
    const int*   __restrict__ shifts,
    const float2* __restrict__ st,
    h16* __restrict__ ygh)             // (B*L, DI) = y * gate(z), f16
{
    int bc   = blockIdx.x / 6;
    int dblk = blockIdx.x % 6;
    int d    = dblk * 256 + threadIdx.x;
    int b    = bc / CHUNKS;
    int chunk= bc % CHUNKS;

    float base[16], p2[16], h[16];
    size_t sb = ((size_t)bc * DII + d) * 16;
    #pragma unroll
    for (int n = 0; n < 16; ++n) {
        base[n] = basenum[d * NSS + n];
        p2[n]   = exp2f(-(float)shifts[d * NSS + n]);
        h[n] = st[sb + n].x;           // incoming prefix
    }
    int row0 = b * LL + chunk * CHLEN;
    #pragma unroll 2
    for (int l = 0; l < CHLEN; ++l) {
        int row = row0 + l;
        float dm = dmbc[(size_t)row * N2 + d];
        float xv = (float)xacth[(size_t)row * DII + d];
        float common = xv * (dspf(dm) * 0.1f);
        const float4* Bp = (const float4*)(dmbc + (size_t)row * N2 + DII);
        float4 B0 = Bp[0], B1 = Bp[1], B2 = Bp[2], B3 = Bp[3];
        float4 C0 = Bp[4], C1 = Bp[5], C2 = Bp[6], C3 = Bp[7];
        const float Bv[16] = {B0.x,B0.y,B0.z,B0.w, B1.x,B1.y,B1.z,B1.w,
                              B2.x,B2.y,B2.z,B2.w, B3.x,B3.y,B3.z,B3.w};
        const float Cv[16] = {C0.x,C0.y,C0.z,C0.w, C1.x,C1.y,C1.z,C1.w,
                              C2.x,C2.y,C2.z,C2.w, C3.x,C3.y,C3.z,C3.w};
        float y = 0.f;
        #pragma unroll
        for (int n = 0; n < 16; ++n) {
            float a = clampf(base[n] + dm, 0.f, 32767.f) * p2[n];
            h[n] = fmaf(a, h[n], common * Bv[n]);
            float hc = clampf(h[n], -32000.f, 32000.f);
            y = fmaf(hc, Cv[n], y);
        }
        float gate = (float)gateh[(size_t)row * DII + d];
        ygh[(size_t)row * DII + d] = (h16)(y * gate);
    }
}

// ---------------------------------------------------------------------------
extern "C" void kernel_launch(void* const* d_in, const int* in_sizes, int n_in,
                              void* d_out, int out_size, void* d_ws, size_t ws_size,
                              hipStream_t stream) {
    const float* hs        = (const float*)d_in[0];
    const float* gamma     = (const float*)d_in[1];
    const float* W_in      = (const float*)d_in[2];
    const float* b_in      = (const float*)d_in[3];
    const float* conv_w    = (const float*)d_in[4];
    const float* conv_b    = (const float*)d_in[5];
    const float* W_x       = (const float*)d_in[6];
    const float* b_x       = (const float*)d_in[7];
    const float* W_dt      = (const float*)d_in[8];
    const float* b_dt      = (const float*)d_in[9];
    const float* W_out     = (const float*)d_in[10];
    const float* b_out     = (const float*)d_in[11];
    const float* base_dec  = (const float*)d_in[12];
    const float* res_gate  = (const float*)d_in[13];
    const int*   dec_shift = (const int*)d_in[14];

    // workspace layout (bytes)
    char* w = (char*)d_ws;
    float* XZ    = (float*)w;  w += (size_t)NROWS * XZN * 4;   // 25165824; later SCST (exact fit)
    h16*   XACTH = (h16*)w;    w += (size_t)NROWS * DII * 2;   // 6291456
    float* DMBC  = (float*)w;  w += (size_t)NROWS * N2  * 4;   // 13631488
    h16*   W2H   = (h16*)w;    w += (size_t)N2 * DII * 2;      // 5111808
    h16*   WOH   = (h16*)w;    w += (size_t)DMM * DII * 2;     // 2359296
    float* BIAS2 = (float*)w;  w += 8192;
    h16*   YGH   = (h16*)w;    w += (size_t)NROWS * DII * 2;   // 6291456
    h16*   HSNH  = (h16*)w;    w += (size_t)NROWS * DMM * 2;   // 3145728
    h16*   WINH  = (h16*)w;    w += (size_t)XZN * DMM * 2;     // 4718592
    // overlays: SCST on XZ (both 25165824 B); GATEH on HSNH+WINH (written by
    // conv, after gemm1 has consumed HSNH/WINH)
    float2* SCST  = (float2*)XZ;
    h16*    GATEH = HSNH;

    float* out = (float*)d_out;

    // 0. weight prep
    k_cvt<<<(XZN * DMM + 255) / 256, 256, 0, stream>>>(W_in, WINH, XZN * DMM);
    k_cvt<<<(DMM * DII + 255) / 256, 256, 0, stream>>>(W_out, WOH, DMM * DII);
    k_w2<<<N2, 256, 0, stream>>>(W_x, b_x, W_dt, b_dt, W2H, BIAS2);

    // 1. norm -> f16
    k_norm<<<NROWS, 256, 0, stream>>>(hs, gamma, HSNH);

    // 2. xz = hsn @ W_in^T + b_in   (2048 x 3072 x 768), fp32 out
    k_gemm_h<0><<<dim3(XZN / 128, NROWS / 128), 256, 0, stream>>>(
        HSNH, DMM, WINH, DMM, b_in, XZ, XZN, DMM, nullptr, nullptr);

    // 3. conv + dsp -> f16 xact; gate(z) -> f16   (XZ dead afterwards)
    k_conv<<<(NROWS * DII) / 256, 256, 0, stream>>>(XZ, conv_w, conv_b, XACTH, GATEH);

    // 4. combined: [decay_mod | B | C] = xact @ W2^T + bias2  (2048 x 1664 x 1536)
    k_gemm_h<0><<<dim3(N2 / 128, NROWS / 128), 256, 0, stream>>>(
        XACTH, DII, W2H, DII, BIAS2, DMBC, N2, DII, nullptr, nullptr);

    // 5. chunked scan (64 chunks x 16) + fused einsum + gate -> ygh (f16)
    k_scan_p1<<<BB * CHUNKS * 6, 256, 0, stream>>>(
        DMBC, XACTH, base_dec, dec_shift, SCST);
    k_scan_p2<<<NCH / 256, 256, 0, stream>>>(SCST);
    k_scan_p3<<<BB * CHUNKS * 6, 256, 0, stream>>>(
        DMBC, XACTH, GATEH, base_dec, dec_shift, SCST, YGH);

    // 6. out = resid + clip(yg @ W_out^T + b_out)*rg   (2048 x 768 x 1536)
    k_gemm_h<1><<<dim3(DMM / 128, NROWS / 128), 256, 0, stream>>>(
        YGH, DII, WOH, DII, b_out, out, DMM, DII, hs, res_gate);
}

// Round 5
// 179.823 us; speedup vs baseline: 6.4344x; 1.1314x over previous
//
#include <hip/hip_runtime.h>
#include <hip/hip_bf16.h>
#include <stdint.h>

// Problem constants
#define BB  2
#define LL  1024
#define DMM 768
#define DII 1536
#define NSS 16
#define DTRR 48
#define XZN (2*DII)        // 3072
#define NROWS (BB*LL)      // 2048
#define N2 1664            // padded N for combined GEMM2 (1536 dmod + 32 B/C + 96 pad)

// chunked scan: one thread per (b, d, chunk), 16 n-states in registers
#define CHUNKS 64
#define CHLEN  (LL/CHUNKS)          // 16
#define NCH    (BB*DII*NSS)         // 49152 channels for p2

typedef _Float16 h16;
typedef __attribute__((ext_vector_type(8))) _Float16 h16x8;
typedef __attribute__((ext_vector_type(4))) float f32x4;

typedef const __attribute__((address_space(1))) uint32_t gau32;
typedef __attribute__((address_space(3))) uint32_t lau32;
#define GLL16(gp, lp) __builtin_amdgcn_global_load_lds((gau32*)(gp), (lau32*)(lp), 16, 0, 0)

__device__ __forceinline__ float dspf(float x) {
    return 0.25f * (x + sqrtf(x*x + 4.0f));
}
__device__ __forceinline__ float clampf(float x, float lo, float hi) {
    return fminf(fmaxf(x, lo), hi);
}

// ---------------------------------------------------------------------------
// f32 -> f16 convert
// ---------------------------------------------------------------------------
__global__ __launch_bounds__(256) void k_cvt(const float* __restrict__ in,
                                             h16* __restrict__ out, int n) {
    int i = blockIdx.x * 256 + threadIdx.x;
    if (i < n) out[i] = (h16)in[i];
}

// ---------------------------------------------------------------------------
// Build combined W2 [N2 x DII] (f16) + bias2 [N2] (f32)
// ---------------------------------------------------------------------------
__global__ __launch_bounds__(256) void k_w2(const float* __restrict__ W_x,
                                            const float* __restrict__ b_x,
                                            const float* __restrict__ W_dt,
                                            const float* __restrict__ b_dt,
                                            h16* __restrict__ W2,
                                            float* __restrict__ bias2) {
    int i = blockIdx.x;
    int tid = threadIdx.x;
    if (i < DII) {
        __shared__ float wd[DTRR];
        if (tid < DTRR) wd[tid] = W_dt[i * DTRR + tid];
        __syncthreads();
        for (int j = tid; j < DII; j += 256) {
            float s = 0.f;
            #pragma unroll
            for (int k = 0; k < DTRR; ++k) s = fmaf(wd[k], W_x[(size_t)k * DII + j], s);
            W2[(size_t)i * DII + j] = (h16)s;
        }
        if (tid == 0) {
            float s = b_dt[i];
            for (int k = 0; k < DTRR; ++k) s = fmaf(wd[k], b_x[k], s);
            bias2[i] = s;
        }
    } else if (i < DII + 2 * NSS) {
        int r = i - DII;
        for (int j = tid; j < DII; j += 256)
            W2[(size_t)i * DII + j] = (h16)W_x[(size_t)(DTRR + r) * DII + j];
        if (tid == 0) bias2[i] = b_x[DTRR + r];
    } else {
        for (int j = tid; j < DII; j += 256) W2[(size_t)i * DII + j] = (h16)0.f;
        if (tid == 0) bias2[i] = 0.f;
    }
}

// ---------------------------------------------------------------------------
// K1: norm -> f16 output
// ---------------------------------------------------------------------------
__global__ __launch_bounds__(256) void k_norm(const float* __restrict__ hs,
                                              const float* __restrict__ gamma,
                                              h16* __restrict__ out) {
    int row = blockIdx.x;
    const float* p = hs + (size_t)row * DMM;
    __shared__ float red[256];
    int tid = threadIdx.x;

    float s = 0.f;
    for (int i = tid; i < DMM; i += 256) s += p[i];
    red[tid] = s; __syncthreads();
    for (int off = 128; off > 0; off >>= 1) {
        if (tid < off) red[tid] += red[tid + off];
        __syncthreads();
    }
    float mean = red[0] / (float)DMM;
    __syncthreads();

    float v = 0.f;
    for (int i = tid; i < DMM; i += 256) { float d = p[i] - mean; v += d*d; }
    red[tid] = v; __syncthreads();
    for (int off = 128; off > 0; off >>= 1) {
        if (tid < off) red[tid] += red[tid + off];
        __syncthreads();
    }
    float var = red[0] / (float)DMM;
    float k = rintf(log2f(sqrtf(var + 1e-9f)));
    k = fmaxf(k, 0.f);
    float scale = exp2f(-k);
    for (int i = tid; i < DMM; i += 256)
        out[(size_t)row * DMM + i] = (h16)((p[i] - mean) * scale * gamma[i]);
}

// ---------------------------------------------------------------------------
// MFMA f16 GEMM, small-matrix regime: 64x64 tile, BK=64, 4 waves (each 32x32),
// DOUBLE-BUFFERED LDS with counted vmcnt(4): next tile's global_load_lds is
// issued before computing the current tile, so HBM/L2 latency hides under
// MFMA+ds_read. Dims must be multiples of 64.
// EPI==1: out = resid + clip(acc+bias,±32000)*rg
// ---------------------------------------------------------------------------
template<int EPI>
__global__ __launch_bounds__(256) void k_gemm64(
    const h16* __restrict__ A, int lda,
    const h16* __restrict__ Bw, int ldb,
    const float* __restrict__ bias,
    float* __restrict__ C, int ldc, int K,
    const float* __restrict__ resid, const float* __restrict__ rgate)
{
    __shared__ __align__(16) h16 As[2][64 * 64];
    __shared__ __align__(16) h16 Bs[2][64 * 64];
    const int tid  = threadIdx.x;
    const int lane = tid & 63;
    const int wv   = tid >> 6;
    const int bm = blockIdx.y * 64, bn = blockIdx.x * 64;
    const int wr = wv >> 1, wc = wv & 1;

    f32x4 acc[2][2] = {};

    // staging: per issue q (0..1), wave wv covers rows (wv*2+q)*8 + srow
    const int srow = lane >> 3;                    // row within 8-row issue
    const int kbl  = ((lane & 7) ^ srow) * 8;      // pre-swizzled logical k-block
    const int KT = K / 64;

    // initial stage into buf 0
    #pragma unroll
    for (int q = 0; q < 2; ++q) {
        int row = (wv * 2 + q) * 8 + srow;
        GLL16(A  + (size_t)(bm + row) * lda + kbl, &As[0][(wv*2+q)*8*64]);
        GLL16(Bw + (size_t)(bn + row) * ldb + kbl, &Bs[0][(wv*2+q)*8*64]);
    }

    int buf = 0;
    for (int kt = 0; kt < KT; ++kt) {
        if (kt + 1 < KT) {
            int k0 = (kt + 1) * 64;
            #pragma unroll
            for (int q = 0; q < 2; ++q) {
                int row = (wv * 2 + q) * 8 + srow;
                GLL16(A  + (size_t)(bm + row) * lda + k0 + kbl, &As[buf^1][(wv*2+q)*8*64]);
                GLL16(Bw + (size_t)(bn + row) * ldb + k0 + kbl, &Bs[buf^1][(wv*2+q)*8*64]);
            }
            asm volatile("s_waitcnt vmcnt(4)" ::: "memory");   // current tile done, next in flight
        } else {
            asm volatile("s_waitcnt vmcnt(0)" ::: "memory");
        }
        __syncthreads();                                       // tile visible to all waves

        const int r16 = lane & 15, kq = lane >> 4;
        #pragma unroll
        for (int kk = 0; kk < 2; ++kk) {
            h16x8 af[2], bf[2];
            #pragma unroll
            for (int i = 0; i < 2; ++i) {
                int rowA = wr * 32 + i * 16 + r16;
                af[i] = *(const h16x8*)&As[buf][rowA * 64 + (((kk*4 + kq) ^ (rowA & 7)) << 3)];
            }
            #pragma unroll
            for (int j = 0; j < 2; ++j) {
                int rowB = wc * 32 + j * 16 + r16;
                bf[j] = *(const h16x8*)&Bs[buf][rowB * 64 + (((kk*4 + kq) ^ (rowB & 7)) << 3)];
            }
            #pragma unroll
            for (int i = 0; i < 2; ++i)
                #pragma unroll
                for (int j = 0; j < 2; ++j)
                    acc[i][j] = __builtin_amdgcn_mfma_f32_16x16x32_f16(af[i], bf[j], acc[i][j], 0, 0, 0);
        }
        __syncthreads();                                       // all reads done before restaging this buf
        buf ^= 1;
    }

    // epilogue: C layout col = lane&15, row = (lane>>4)*4 + reg
    const int r4 = (lane >> 4) * 4;
    const int cn = lane & 15;
    float rg = 0.f;
    if (EPI) rg = rgate[0];
    #pragma unroll
    for (int i = 0; i < 2; ++i) {
        #pragma unroll
        for (int j = 0; j < 2; ++j) {
            int col = bn + wc * 32 + j * 16 + cn;
            float bv = bias[col];
            #pragma unroll
            for (int r = 0; r < 4; ++r) {
                int row = bm + wr * 32 + i * 16 + r4 + r;
                float v = acc[i][j][r] + bv;
                if (EPI) {
                    v = clampf(v, -32000.f, 32000.f);
                    v = resid[(size_t)row * ldc + col] + v * rg;
                }
                C[(size_t)row * ldc + col] = v;
            }
        }
    }
}

// ---------------------------------------------------------------------------
// K3: depthwise causal conv + dsp -> f16 xact; also gate(z) -> f16
// ---------------------------------------------------------------------------
__global__ __launch_bounds__(256) void k_conv(const float* __restrict__ xz,
                                              const float* __restrict__ cw,
                                              const float* __restrict__ cb,
                                              h16* __restrict__ xacth,
                                              h16* __restrict__ gateh)
{
    int idx = blockIdx.x * 256 + threadIdx.x;       // over B*L*DI
    if (idx >= NROWS * DII) return;
    int c = idx % DII;
    int bl = idx / DII;
    int l = bl % LL;
    int b = bl / LL;
    float acc = cb[c];
    #pragma unroll
    for (int j = 0; j < 4; ++j) {
        int ls = l - 3 + j;
        if (ls >= 0)
            acc = fmaf(xz[(size_t)(b * LL + ls) * XZN + c], cw[c * 4 + j], acc);
    }
    xacth[idx] = (h16)dspf(acc);
    float z = xz[(size_t)bl * XZN + DII + c];
    gateh[idx] = (h16)(0.5f * (1.0f + z * rsqrtf(z * z + 1.0f)));
}

// ---------------------------------------------------------------------------
// Chunked scan. Thread = (b, chunk, d); 16 n-states in registers.
// ---------------------------------------------------------------------------
__global__ __launch_bounds__(256) void k_scan_p1(
    const float* __restrict__ dmbc,    // (B*L, N2): [dmod 1536 | B 16 | C 16 | pad]
    const h16*   __restrict__ xacth,   // (B*L, DI)
    const float* __restrict__ basenum, // (DI, NS)
    const int*   __restrict__ shifts,  // (DI, NS)
    float2* __restrict__ st)
{
    int bc   = blockIdx.x / 6;              // b*CHUNKS + chunk  (uniform)
    int dblk = blockIdx.x % 6;
    int d    = dblk * 256 + threadIdx.x;
    int b    = bc / CHUNKS;
    int chunk= bc % CHUNKS;

    float base[16], p2[16], h[16], A[16];
    #pragma unroll
    for (int n = 0; n < 16; ++n) {
        base[n] = basenum[d * NSS + n];
        p2[n]   = exp2f(-(float)shifts[d * NSS + n]);
        h[n] = 0.f; A[n] = 1.f;
    }
    int row0 = b * LL + chunk * CHLEN;
    #pragma unroll 2
    for (int l = 0; l < CHLEN; ++l) {
        int row = row0 + l;
        float dm = dmbc[(size_t)row * N2 + d];
        float xv = (float)xacth[(size_t)row * DII + d];
        float common = xv * (dspf(dm) * 0.1f);
        const float4* Bp = (const float4*)(dmbc + (size_t)row * N2 + DII);
        float4 B0 = Bp[0], B1 = Bp[1], B2 = Bp[2], B3 = Bp[3];
        const float Bv[16] = {B0.x,B0.y,B0.z,B0.w, B1.x,B1.y,B1.z,B1.w,
                              B2.x,B2.y,B2.z,B2.w, B3.x,B3.y,B3.z,B3.w};
        #pragma unroll
        for (int n = 0; n < 16; ++n) {
            float a = clampf(base[n] + dm, 0.f, 32767.f) * p2[n];
            h[n] = fmaf(a, h[n], common * Bv[n]);
            A[n] *= a;
        }
    }
    size_t sb = ((size_t)bc * DII + d) * 16;
    #pragma unroll
    for (int n = 0; n < 16; ++n) st[sb + n] = make_float2(A[n], h[n]);
}

__global__ __launch_bounds__(256) void k_scan_p2(float2* __restrict__ st)
{
    int ch = blockIdx.x * 256 + threadIdx.x;   // b*(DII*NSS) + d*16 + n
    int b  = ch / (DII * NSS);
    int rem = ch - b * (DII * NSS);
    float hin = 0.f;
    #pragma unroll 4
    for (int c = 0; c < CHUNKS; ++c) {
        size_t idx = ((size_t)(b * CHUNKS + c) * (DII * NSS)) + rem;
        float2 s = st[idx];
        st[idx].x = hin;
        hin = fmaf(s.x, hin, s.y);
    }
}

__global__ __launch_bounds__(256) void k_scan_p3(
    const float* __restrict__ dmbc,
    const h16*   __restrict__ xacth,
    const h16*   __restrict__ gateh,
    const float* __restrict__ basenum,
    const int*   __restrict__ shifts,
    const float2* __restrict__ st,
    h16* __restrict__ ygh)             // (B*L, DI) = y * gate(z), f16
{
    int bc   = blockIdx.x / 6;
    int dblk = blockIdx.x % 6;
    int d    = dblk * 256 + threadIdx.x;
    int b    = bc / CHUNKS;
    int chunk= bc % CHUNKS;

    float base[16], p2[16], h[16];
    size_t sb = ((size_t)bc * DII + d) * 16;
    #pragma unroll
    for (int n = 0; n < 16; ++n) {
        base[n] = basenum[d * NSS + n];
        p2[n]   = exp2f(-(float)shifts[d * NSS + n]);
        h[n] = st[sb + n].x;           // incoming prefix
    }
    int row0 = b * LL + chunk * CHLEN;
    #pragma unroll 2
    for (int l = 0; l < CHLEN; ++l) {
        int row = row0 + l;
        float dm = dmbc[(size_t)row * N2 + d];
        float xv = (float)xacth[(size_t)row * DII + d];
        float common = xv * (dspf(dm) * 0.1f);
        const float4* Bp = (const float4*)(dmbc + (size_t)row * N2 + DII);
        float4 B0 = Bp[0], B1 = Bp[1], B2 = Bp[2], B3 = Bp[3];
        float4 C0 = Bp[4], C1 = Bp[5], C2 = Bp[6], C3 = Bp[7];
        const float Bv[16] = {B0.x,B0.y,B0.z,B0.w, B1.x,B1.y,B1.z,B1.w,
                              B2.x,B2.y,B2.z,B2.w, B3.x,B3.y,B3.z,B3.w};
        const float Cv[16] = {C0.x,C0.y,C0.z,C0.w, C1.x,C1.y,C1.z,C1.w,
                              C2.x,C2.y,C2.z,C2.w, C3.x,C3.y,C3.z,C3.w};
        float y = 0.f;
        #pragma unroll
        for (int n = 0; n < 16; ++n) {
            float a = clampf(base[n] + dm, 0.f, 32767.f) * p2[n];
            h[n] = fmaf(a, h[n], common * Bv[n]);
            float hc = clampf(h[n], -32000.f, 32000.f);
            y = fmaf(hc, Cv[n], y);
        }
        float gate = (float)gateh[(size_t)row * DII + d];
        ygh[(size_t)row * DII + d] = (h16)(y * gate);
    }
}

// ---------------------------------------------------------------------------
extern "C" void kernel_launch(void* const* d_in, const int* in_sizes, int n_in,
                              void* d_out, int out_size, void* d_ws, size_t ws_size,
                              hipStream_t stream) {
    const float* hs        = (const float*)d_in[0];
    const float* gamma     = (const float*)d_in[1];
    const float* W_in      = (const float*)d_in[2];
    const float* b_in      = (const float*)d_in[3];
    const float* conv_w    = (const float*)d_in[4];
    const float* conv_b    = (const float*)d_in[5];
    const float* W_x       = (const float*)d_in[6];
    const float* b_x       = (const float*)d_in[7];
    const float* W_dt      = (const float*)d_in[8];
    const float* b_dt      = (const float*)d_in[9];
    const float* W_out     = (const float*)d_in[10];
    const float* b_out     = (const float*)d_in[11];
    const float* base_dec  = (const float*)d_in[12];
    const float* res_gate  = (const float*)d_in[13];
    const int*   dec_shift = (const int*)d_in[14];

    // workspace layout (bytes)
    char* w = (char*)d_ws;
    float* XZ    = (float*)w;  w += (size_t)NROWS * XZN * 4;   // 25165824; later SCST (exact fit)
    h16*   XACTH = (h16*)w;    w += (size_t)NROWS * DII * 2;   // 6291456
    float* DMBC  = (float*)w;  w += (size_t)NROWS * N2  * 4;   // 13631488
    h16*   W2H   = (h16*)w;    w += (size_t)N2 * DII * 2;      // 5111808
    h16*   WOH   = (h16*)w;    w += (size_t)DMM * DII * 2;     // 2359296
    float* BIAS2 = (float*)w;  w += 8192;
    h16*   YGH   = (h16*)w;    w += (size_t)NROWS * DII * 2;   // 6291456
    h16*   HSNH  = (h16*)w;    w += (size_t)NROWS * DMM * 2;   // 3145728
    h16*   WINH  = (h16*)w;    w += (size_t)XZN * DMM * 2;     // 4718592
    // overlays: SCST on XZ (both 25165824 B); GATEH on HSNH+WINH (written by
    // conv, after gemm1 has consumed HSNH/WINH)
    float2* SCST  = (float2*)XZ;
    h16*    GATEH = HSNH;

    float* out = (float*)d_out;

    // 0. weight prep
    k_cvt<<<(XZN * DMM + 255) / 256, 256, 0, stream>>>(W_in, WINH, XZN * DMM);
    k_cvt<<<(DMM * DII + 255) / 256, 256, 0, stream>>>(W_out, WOH, DMM * DII);
    k_w2<<<N2, 256, 0, stream>>>(W_x, b_x, W_dt, b_dt, W2H, BIAS2);

    // 1. norm -> f16
    k_norm<<<NROWS, 256, 0, stream>>>(hs, gamma, HSNH);

    // 2. xz = hsn @ W_in^T + b_in   (2048 x 3072 x 768), fp32 out
    k_gemm64<0><<<dim3(XZN / 64, NROWS / 64), 256, 0, stream>>>(
        HSNH, DMM, WINH, DMM, b_in, XZ, XZN, DMM, nullptr, nullptr);

    // 3. conv + dsp -> f16 xact; gate(z) -> f16   (XZ dead afterwards)
    k_conv<<<(NROWS * DII) / 256, 256, 0, stream>>>(XZ, conv_w, conv_b, XACTH, GATEH);

    // 4. combined: [decay_mod | B | C] = xact @ W2^T + bias2  (2048 x 1664 x 1536)
    k_gemm64<0><<<dim3(N2 / 64, NROWS / 64), 256, 0, stream>>>(
        XACTH, DII, W2H, DII, BIAS2, DMBC, N2, DII, nullptr, nullptr);

    // 5. chunked scan (64 chunks x 16) + fused einsum + gate -> ygh (f16)
    k_scan_p1<<<BB * CHUNKS * 6, 256, 0, stream>>>(
        DMBC, XACTH, base_dec, dec_shift, SCST);
    k_scan_p2<<<NCH / 256, 256, 0, stream>>>(SCST);
    k_scan_p3<<<BB * CHUNKS * 6, 256, 0, stream>>>(
        DMBC, XACTH, GATEH, base_dec, dec_shift, SCST, YGH);

    // 6. out = resid + clip(yg @ W_out^T + b_out)*rg   (2048 x 768 x 1536)
    k_gemm64<1><<<dim3(DMM / 64, NROWS / 64), 256, 0, stream>>>(
        YGH, DII, WOH, DII, b_out, out, DMM, DII, hs, res_gate);
}